// Round 3
// baseline (12775.636 us; speedup 1.0000x reference)
//
#include <hip/hip_runtime.h>
#include <math.h>

// EQGAT edge GNN, fp32 baseline, ws_size-adaptive layout.
// Fixed workspace: ~125.5 MB; edge h-buffer chunked into the remainder.

constexpr int NN  = 10000;   // nodes
constexpr int NE  = 160000;  // edges
constexpr int SD  = 256;     // SDIM
constexpr int VD  = 128;     // VDIM
constexpr int EFD = 88;      // rbf(20)+a(1)+e(32)+ohe(3)+g(32)
constexpr int DIN_ = 600;

static __device__ __forceinline__ float silu_f(float x) {
  return x / (1.0f + expf(-x));
}

// ---------------- setup: rbf table + in-degree ----------------
__global__ __launch_bounds__(256) void k_setup(
    const float* __restrict__ edge_d, const int* __restrict__ tgt,
    float* __restrict__ rbfE, float* __restrict__ cnt)
{
  int e = blockIdx.x * 256 + threadIdx.x;
  if (e >= NE) return;
  float d = edge_d[e];
  float env = 0.0f;
  if (d < 5.0f) env = 0.5f * cosf(d * 0.628318530717958648f) + 0.5f; // pi/5
  #pragma unroll
  for (int j = 0; j < 20; ++j) {
    float mu = (5.0f / 19.0f) * (float)j;     // linspace(0,5,20)
    float x = d - mu;
    rbfE[e * 20 + j] = env * expf(-8.0f * x * x); // coeff = -0.5/(0.25^2)
  }
  atomicAdd(&cnt[tgt[e]], 1.0f);
}

__global__ __launch_bounds__(256) void k_invcnt(
    const float* __restrict__ cnt, float* __restrict__ icnt)
{
  int n = blockIdx.x * 256 + threadIdx.x;
  if (n < NN) icnt[n] = 1.0f / fmaxf(cnt[n], 1.0f);
}

// ---------------- LayerNorm(s) + vnorm(v), with optional copies ----------------
__global__ __launch_bounds__(256) void k_ln_vnorm(
    const float* __restrict__ s, const float* __restrict__ v,
    const float* __restrict__ gamma, const float* __restrict__ beta,
    float* __restrict__ s_ln, float* __restrict__ s_copy,
    float* __restrict__ v_n, float* __restrict__ v_copy)
{
  int n = blockIdx.x, t = threadIdx.x;
  __shared__ float red[8];
  float x = s[n * SD + t];
  float ss = x, sq = x * x;
  #pragma unroll
  for (int o = 32; o > 0; o >>= 1) { ss += __shfl_down(ss, o); sq += __shfl_down(sq, o); }
  int wid = t >> 6;
  if ((t & 63) == 0) { red[wid * 2] = ss; red[wid * 2 + 1] = sq; }
  __syncthreads();
  if (t == 0) {
    float S = red[0] + red[2] + red[4] + red[6];
    float Q = red[1] + red[3] + red[5] + red[7];
    float mu = S * (1.0f / SD);
    float var = Q * (1.0f / SD) - mu * mu;
    red[0] = mu; red[1] = rsqrtf(var + 1e-6f);
  }
  __syncthreads();
  float mu = red[0], rstd = red[1];
  float y = (x - mu) * rstd * gamma[t] + beta[t];
  s_ln[n * SD + t] = y;
  if (s_copy) s_copy[n * SD + t] = y;
  __syncthreads();
  // vnorm: f = sqrt(mean_w(sum_c v^2) + eps), per-node scalar over 384 vals
  float v0 = v[n * 384 + t];
  float v1 = (t < 128) ? v[n * 384 + 256 + t] : 0.0f;
  float q = v0 * v0 + v1 * v1;
  #pragma unroll
  for (int o = 32; o > 0; o >>= 1) q += __shfl_down(q, o);
  if ((t & 63) == 0) red[wid] = q;
  __syncthreads();
  if (t == 0) red[4] = rsqrtf((red[0] + red[1] + red[2] + red[3]) * (1.0f / VD) + 1e-6f);
  __syncthreads();
  float rf = red[4];
  float w0 = v0 * rf;
  v_n[n * 384 + t] = w0;
  if (v_copy) v_copy[n * 384 + t] = w0;
  if (t < 128) {
    float w1 = v1 * rf;
    v_n[n * 384 + 256 + t] = w1;
    if (v_copy) v_copy[n * 384 + 256 + t] = w1;
  }
}

// ---------------- generic fp32 GEMM: C[M,N] = op(A[M,K] @ W[K,N] + bias) ----------------
// 64x64 tile, BK=16, 256 threads, 4x4 micro-tile. K multiple of 16,
// N (cols) multiple of 64; M guarded.
template<int DO_SILU>
__global__ __launch_bounds__(256) void k_gemm(
    const float* __restrict__ A, int lda,
    const float* __restrict__ W, int ldw,
    const float* __restrict__ bias,
    float* __restrict__ C, int ldc,
    int M, int K)
{
  __shared__ float As[16][66];
  __shared__ float Ws[16][66];
  int row0 = blockIdx.y * 64, col0 = blockIdx.x * 64;
  int tid = threadIdx.x;
  int tx = tid & 15, ty = tid >> 4;
  float acc[4][4] = {};
  for (int k0 = 0; k0 < K; k0 += 16) {
    __syncthreads();
    {
      int r = tid >> 2, kk0 = (tid & 3) * 4;
      float4 a = make_float4(0.f, 0.f, 0.f, 0.f);
      if (row0 + r < M) a = *(const float4*)&A[(size_t)(row0 + r) * lda + k0 + kk0];
      As[kk0 + 0][r] = a.x; As[kk0 + 1][r] = a.y; As[kk0 + 2][r] = a.z; As[kk0 + 3][r] = a.w;
    }
    {
      int kk = tid >> 4, c0 = (tid & 15) * 4;
      float4 w4 = *(const float4*)&W[(size_t)(k0 + kk) * ldw + col0 + c0];
      Ws[kk][c0 + 0] = w4.x; Ws[kk][c0 + 1] = w4.y; Ws[kk][c0 + 2] = w4.z; Ws[kk][c0 + 3] = w4.w;
    }
    __syncthreads();
    #pragma unroll
    for (int kk = 0; kk < 16; ++kk) {
      float a[4], b[4];
      #pragma unroll
      for (int i = 0; i < 4; ++i) a[i] = As[kk][ty * 4 + i];
      #pragma unroll
      for (int j = 0; j < 4; ++j) b[j] = Ws[kk][tx * 4 + j];
      #pragma unroll
      for (int i = 0; i < 4; ++i)
        #pragma unroll
        for (int j = 0; j < 4; ++j) acc[i][j] += a[i] * b[j];
    }
  }
  #pragma unroll
  for (int i = 0; i < 4; ++i) {
    int r = row0 + ty * 4 + i;
    if (r >= M) continue;
    #pragma unroll
    for (int j = 0; j < 4; ++j) {
      int c = col0 + tx * 4 + j;
      float val = acc[i][j] + (bias ? bias[c] : 0.0f);
      if (DO_SILU) val = silu_f(val);
      C[(size_t)r * ldc + c] = val;
    }
  }
}

// ---------------- h = silu(pre1[src] + pre2[tgt] + ef@W1c + be1) ----------------
// block: 32 edges x 256 cols; thread: 2 edges x 16 cols (col = cg + 16*u)
// Processes edges [e0 + blockIdx.x*32, +32); h is indexed chunk-locally.
__global__ __launch_bounds__(256) void k_h(
    const float* __restrict__ rbfE, const float* __restrict__ edge_a,
    const float* __restrict__ edge_e, const float* __restrict__ edge_ohe,
    const float* __restrict__ edge_g,
    const int* __restrict__ src, const int* __restrict__ tgt,
    const float* __restrict__ pre12,
    const float* __restrict__ W1c,   // We1 rows 512..599 -> [88][256]
    const float* __restrict__ be1,
    int e0,
    float* __restrict__ h)
{
  __shared__ float efs[32][EFD];
  __shared__ float wc[8][SD];
  int le0 = blockIdx.x * 32;       // chunk-local
  int ge0 = e0 + le0;              // global edge id
  int tid = threadIdx.x;
  for (int slot = tid; slot < 32 * EFD; slot += 256) {
    int el = slot / EFD, j = slot - el * EFD;
    int e = ge0 + el;
    float val;
    if (j < 20)       val = rbfE[e * 20 + j];
    else if (j == 20) val = edge_a[e];
    else if (j < 53)  val = edge_e[e * 32 + (j - 21)];
    else if (j < 56)  val = edge_ohe[e * 3 + (j - 53)];
    else              val = edge_g[e * 32 + (j - 56)];
    efs[el][j] = val;
  }
  int cg = tid & 15, er = tid >> 4;
  int eA = ge0 + er * 2, eB = eA + 1;
  float acc0[16] = {}, acc1[16] = {};
  for (int j0 = 0; j0 < EFD; j0 += 8) {
    __syncthreads();
    for (int sl = tid; sl < 8 * SD; sl += 256) {
      int jj = sl >> 8, c = sl & 255;
      wc[jj][c] = W1c[(j0 + jj) * SD + c];
    }
    __syncthreads();
    #pragma unroll
    for (int jj = 0; jj < 8; ++jj) {
      float a0 = efs[er * 2][j0 + jj];
      float a1 = efs[er * 2 + 1][j0 + jj];
      #pragma unroll
      for (int u = 0; u < 16; ++u) {
        float wv = wc[jj][cg + 16 * u];
        acc0[u] += a0 * wv;
        acc1[u] += a1 * wv;
      }
    }
  }
  int sA = src[eA], tA = tgt[eA], sB = src[eB], tB = tgt[eB];
  size_t hA = (size_t)(le0 + er * 2) * SD;
  #pragma unroll
  for (int u = 0; u < 16; ++u) {
    int c = cg + 16 * u;
    float b = be1[c];
    float x0 = acc0[u] + pre12[(size_t)sA * 512 + c] + pre12[(size_t)tA * 512 + 256 + c] + b;
    float x1 = acc1[u] + pre12[(size_t)sB * 512 + c] + pre12[(size_t)tB * 512 + 256 + c] + b;
    h[hA + c] = silu_f(x0);
    h[hA + SD + c] = silu_f(x1);
  }
}

// ---------------- m = h @ We2 + be2, fused scatter into s_next / v_next ----------------
// grid: (chunkE/128, 4). cg 0/1: ms cols [cg*128, +128). cg 2/3: gr/gv k-range
// [(cg-2)*64, +64) with (gr[k], gv[k]) interleaved in the W tile.
// Edges [e0 + blockIdx.x*128, +128); h indexed chunk-locally.
__global__ __launch_bounds__(256) void k_m_scatter(
    const float* __restrict__ h, const float* __restrict__ We2,
    const float* __restrict__ be2,
    const int* __restrict__ src, const int* __restrict__ tgt,
    const float* __restrict__ icnt, const float* __restrict__ rnorm,
    const float* __restrict__ v_n,
    int e0,
    float* __restrict__ s_next, float* __restrict__ v_next)
{
  __shared__ float As[16][132];
  __shared__ float Ws[16][132];
  __shared__ int   sm_tgt[128];
  __shared__ int   sm_src[128];
  __shared__ float sm_ic[128];
  __shared__ float sm_rn[128 * 3];
  int le0 = blockIdx.x * 128;      // chunk-local
  int ge0 = e0 + le0;              // global
  int cg = blockIdx.y;
  int tid = threadIdx.x;
  int tx = tid & 15, ty = tid >> 4;
  float acc[8][8] = {};
  for (int k0 = 0; k0 < 256; k0 += 16) {
    __syncthreads();
    {
      int r = tid >> 1, kk0 = (tid & 1) * 8;
      const float4* hp = (const float4*)&h[(size_t)(le0 + r) * SD + k0 + kk0];
      float4 u0 = hp[0], u1 = hp[1];
      As[kk0 + 0][r] = u0.x; As[kk0 + 1][r] = u0.y; As[kk0 + 2][r] = u0.z; As[kk0 + 3][r] = u0.w;
      As[kk0 + 4][r] = u1.x; As[kk0 + 5][r] = u1.y; As[kk0 + 6][r] = u1.z; As[kk0 + 7][r] = u1.w;
    }
    {
      int kk = tid >> 4, j0 = (tid & 15) * 8;
      const float* wrow = &We2[(size_t)(k0 + kk) * 512];
      if (cg < 2) {
        const float4* wp = (const float4*)&wrow[cg * 128 + j0];
        float4 w0 = wp[0], w1 = wp[1];
        Ws[kk][j0 + 0] = w0.x; Ws[kk][j0 + 1] = w0.y; Ws[kk][j0 + 2] = w0.z; Ws[kk][j0 + 3] = w0.w;
        Ws[kk][j0 + 4] = w1.x; Ws[kk][j0 + 5] = w1.y; Ws[kk][j0 + 6] = w1.z; Ws[kk][j0 + 7] = w1.w;
      } else {
        int kv0 = (cg - 2) * 64 + j0 / 2;
        float4 wg = *(const float4*)&wrow[256 + kv0];
        float4 wv = *(const float4*)&wrow[384 + kv0];
        Ws[kk][j0 + 0] = wg.x; Ws[kk][j0 + 1] = wv.x;
        Ws[kk][j0 + 2] = wg.y; Ws[kk][j0 + 3] = wv.y;
        Ws[kk][j0 + 4] = wg.z; Ws[kk][j0 + 5] = wv.z;
        Ws[kk][j0 + 6] = wg.w; Ws[kk][j0 + 7] = wv.w;
      }
    }
    __syncthreads();
    #pragma unroll
    for (int kk = 0; kk < 16; ++kk) {
      float a[8], b[8];
      #pragma unroll
      for (int i = 0; i < 8; ++i) a[i] = As[kk][ty * 8 + i];
      #pragma unroll
      for (int j = 0; j < 8; ++j) b[j] = Ws[kk][tx * 8 + j];
      #pragma unroll
      for (int i = 0; i < 8; ++i)
        #pragma unroll
        for (int j = 0; j < 8; ++j) acc[i][j] += a[i] * b[j];
    }
  }
  if (tid < 128) {
    int e = ge0 + tid;
    int t = tgt[e];
    sm_tgt[tid] = t;
    sm_ic[tid]  = icnt[t];
    sm_src[tid] = src[e];
    sm_rn[tid * 3 + 0] = rnorm[(size_t)e * 3 + 0];
    sm_rn[tid * 3 + 1] = rnorm[(size_t)e * 3 + 1];
    sm_rn[tid * 3 + 2] = rnorm[(size_t)e * 3 + 2];
  }
  __syncthreads();
  if (cg < 2) {
    int cbase = cg * 128 + tx * 8;
    float bb[8];
    #pragma unroll
    for (int j = 0; j < 8; ++j) bb[j] = be2[cbase + j];
    #pragma unroll
    for (int i = 0; i < 8; ++i) {
      int r = ty * 8 + i;
      int t = sm_tgt[r];
      float ic = sm_ic[r];
      float* dst = &s_next[(size_t)t * SD + cbase];
      #pragma unroll
      for (int j = 0; j < 8; ++j)
        atomicAdd(&dst[j], (acc[i][j] + bb[j]) * ic);
    }
  } else {
    int kb = (cg - 2) * 64 + tx * 4;
    float bg[4], bv[4];
    #pragma unroll
    for (int m = 0; m < 4; ++m) { bg[m] = be2[256 + kb + m]; bv[m] = be2[384 + kb + m]; }
    #pragma unroll
    for (int i = 0; i < 8; ++i) {
      int r = ty * 8 + i;
      int t = sm_tgt[r], sn = sm_src[r];
      float ic = sm_ic[r];
      float r0 = sm_rn[r * 3 + 0], r1 = sm_rn[r * 3 + 1], r2 = sm_rn[r * 3 + 2];
      #pragma unroll
      for (int m = 0; m < 4; ++m) {
        int kv = kb + m;
        float gr = acc[i][2 * m] + bg[m];
        float gv = acc[i][2 * m + 1] + bv[m];
        float vs0 = v_n[(size_t)sn * 384 + 0 * VD + kv];
        float vs1 = v_n[(size_t)sn * 384 + 1 * VD + kv];
        float vs2 = v_n[(size_t)sn * 384 + 2 * VD + kv];
        atomicAdd(&v_next[(size_t)t * 384 + 0 * VD + kv], ic * (gr * r0 + gv * vs0));
        atomicAdd(&v_next[(size_t)t * 384 + 1 * VD + kv], ic * (gr * r1 + gv * vs1));
        atomicAdd(&v_next[(size_t)t * 384 + 2 * VD + kv], ic * (gr * r2 + gv * vs2));
      }
    }
  }
}

// ---------------- nv = sqrt(sum_c vv^2 + eps); xcat = [s | nv] ----------------
__global__ __launch_bounds__(256) void k_nv_xcat(
    const float* __restrict__ vv, const float* __restrict__ s_next,
    float* __restrict__ xcat)
{
  int n = blockIdx.x, t = threadIdx.x;
  xcat[(size_t)n * 384 + t] = s_next[(size_t)n * SD + t];
  if (t < 128) {
    float a = vv[(size_t)(n * 3 + 0) * VD + t];
    float b = vv[(size_t)(n * 3 + 1) * VD + t];
    float c = vv[(size_t)(n * 3 + 2) * VD + t];
    xcat[(size_t)n * 384 + 256 + t] = sqrtf(a * a + b * b + c * c + 1e-6f);
  }
}

// ---------------- s_cur = s_next + u[:, :256]; v_cur = v_next + vv * u[:, None, 256:] ----------------
__global__ __launch_bounds__(256) void k_update(
    const float* __restrict__ s_next, const float* __restrict__ v_next,
    const float* __restrict__ vv, const float* __restrict__ u,
    float* __restrict__ s_cur, float* __restrict__ v_cur)
{
  int i = blockIdx.x * 256 + threadIdx.x;
  const int NVT = NN * 384;
  if (i < NVT) {
    int n = i / 384;
    int k = (i - n * 384) & 127;
    v_cur[i] = v_next[i] + vv[i] * u[(size_t)n * 384 + 256 + k];
  } else {
    int j = i - NVT;
    if (j < NN * SD) {
      int n = j >> 8, c = j & 255;
      s_cur[j] = s_next[j] + u[(size_t)n * 384 + c];
    }
  }
}

// =====================================================================
extern "C" void kernel_launch(void* const* d_in, const int* in_sizes, int n_in,
                              void* d_out, int out_size, void* d_ws, size_t ws_size,
                              hipStream_t stream)
{
  const float* s_in   = (const float*)d_in[0];
  const float* v_in   = (const float*)d_in[1];
  const float* p_in   = (const float*)d_in[2];
  const int*   eidx   = (const int*)d_in[3];
  const float* edge_d = (const float*)d_in[4];
  const float* edge_a = (const float*)d_in[5];
  const float* rnorm  = (const float*)d_in[6];
  const float* edge_e = (const float*)d_in[7];
  const float* edge_o = (const float*)d_in[8];
  const float* edge_g = (const float*)d_in[9];
  const float* gamma  = (const float*)d_in[10];
  const float* beta   = (const float*)d_in[11];
  const float* We1    = (const float*)d_in[12];
  const float* be1    = (const float*)d_in[13];
  const float* We2    = (const float*)d_in[14];
  const float* be2    = (const float*)d_in[15];
  const float* Wvu    = (const float*)d_in[16];
  const float* Wu1    = (const float*)d_in[17];
  const float* bu1    = (const float*)d_in[18];
  const float* Wu2    = (const float*)d_in[19];
  const float* bu2    = (const float*)d_in[20];
  const int* srcA = eidx;
  const int* tgtA = eidx + NE;

  float* w = (float*)d_ws;
  float* s_cur  = w; w += NN * SD;
  float* v_cur  = w; w += NN * 384;
  float* s_ln   = w; w += NN * SD;      // reused later as tbuf
  float* v_nrm  = w; w += NN * 384;     // reused later as ubuf
  float* s_next = w; w += NN * SD;
  float* v_next = w; w += NN * 384;
  float* pre12  = w; w += NN * 512;     // reused later as xcat (N*384)
  float* rbfE   = w; w += (size_t)NE * 20;
  float* cnt    = w; w += NN;
  float* icnt   = w; w += NN;
  float* vv     = w; w += NN * 384;
  float* hbuf   = w;                     // rest of workspace
  float* tbuf = s_ln;
  float* ubuf = v_nrm;
  float* xcat = pre12;

  // edge chunking sized to remaining workspace (deterministic: ws_size is constant)
  size_t fixedF = (size_t)(hbuf - (float*)d_ws);
  size_t totalF = ws_size / sizeof(float);
  size_t availF = (totalF > fixedF) ? (totalF - fixedF) : 0;
  long long mc = (long long)(availF / SD) & ~127LL;   // multiple of 128 edges
  if (mc > NE) mc = NE;
  if (mc < 128) mc = 128;
  const int chunkE = (int)mc;

  hipMemsetAsync(cnt, 0, NN * sizeof(float), stream);
  k_setup<<<(NE + 255) / 256, 256, 0, stream>>>(edge_d, tgtA, rbfE, cnt);
  k_invcnt<<<(NN + 255) / 256, 256, 0, stream>>>(cnt, icnt);

  const float* sp = s_in;
  const float* vp = v_in;
  for (int i = 0; i < 5; ++i) {
    k_ln_vnorm<<<NN, 256, 0, stream>>>(sp, vp, gamma + i * SD, beta + i * SD,
                                       s_ln, s_next, v_nrm, v_next);
    const float* W1 = We1 + (size_t)i * DIN_ * SD;
    // pre1 (s[src] part) and pre2 (s[tgt] part), stored side by side [N,512]
    k_gemm<0><<<dim3(4, 157), 256, 0, stream>>>(s_ln, SD, W1, SD, nullptr,
                                                pre12, 512, NN, SD);
    k_gemm<0><<<dim3(4, 157), 256, 0, stream>>>(s_ln, SD, W1 + 256 * SD, SD, nullptr,
                                                pre12 + 256, 512, NN, SD);
    for (int e0 = 0; e0 < NE; e0 += chunkE) {
      int ce = NE - e0; if (ce > chunkE) ce = chunkE;
      k_h<<<ce / 32, 256, 0, stream>>>(rbfE, edge_a, edge_e, edge_o, edge_g,
                                       srcA, tgtA, pre12, W1 + 512 * SD,
                                       be1 + i * SD, e0, hbuf);
      k_m_scatter<<<dim3(ce / 128, 4), 256, 0, stream>>>(
          hbuf, We2 + (size_t)i * SD * 512, be2 + i * 512,
          srcA, tgtA, icnt, rnorm, v_nrm, e0, s_next, v_next);
    }
    if (i < 4) {
      k_gemm<0><<<dim3(2, 469), 256, 0, stream>>>(v_next, VD, Wvu + i * VD * VD, VD,
                                                  nullptr, vv, VD, 3 * NN, VD);
      k_nv_xcat<<<NN, 256, 0, stream>>>(vv, s_next, xcat);
      k_gemm<1><<<dim3(4, 157), 256, 0, stream>>>(xcat, 384, Wu1 + (size_t)i * 384 * SD, SD,
                                                  bu1 + i * SD, tbuf, SD, NN, 384);
      k_gemm<0><<<dim3(6, 157), 256, 0, stream>>>(tbuf, SD, Wu2 + (size_t)i * SD * 384, 384,
                                                  bu2 + i * 384, ubuf, 384, NN, SD);
      k_update<<<(NN * 640 + 255) / 256, 256, 0, stream>>>(s_next, v_next, vv, ubuf,
                                                           s_cur, v_cur);
      sp = s_cur; vp = v_cur;
    }
  }
  float* out = (float*)d_out;
  // final LN + vnorm straight into d_out
  k_ln_vnorm<<<NN, 256, 0, stream>>>(s_next, v_next, gamma + 5 * SD, beta + 5 * SD,
                                     out, nullptr, out + NN * SD, nullptr);
  float* outp = out + (size_t)NN * SD + (size_t)NN * 384;
  hipMemcpyAsync(outp, p_in, NN * 3 * sizeof(float), hipMemcpyDeviceToDevice, stream);
  hipMemcpyAsync(outp + NN * 3, edge_e, (size_t)NE * 32 * sizeof(float),
                 hipMemcpyDeviceToDevice, stream);
}

// Round 9
// 4553.036 us; speedup vs baseline: 2.8060x; 2.8060x over previous
//
#include <hip/hip_runtime.h>
#include <math.h>

// EQGAT edge GNN — round 7/8/9: atomic-free aggregation + split-bf16 MFMA g-GEMM.
// Edges counting-sorted by target; h stored as bf16 hi/lo; g = h @ Wg via
// mfma_f32_16x16x32_bf16 (3-term split => ~fp32 accuracy); per-node
// contiguous gather (no atomics); s-half factored through segment-sum.

constexpr int NN  = 10000;   // nodes
constexpr int NE  = 160000;  // edges
constexpr int SD  = 256;     // SDIM
constexpr int VD  = 128;     // VDIM
constexpr int EFD = 88;      // rbf(20)+a(1)+e(32)+ohe(3)+g(32)
constexpr int DIN_ = 600;

typedef __attribute__((ext_vector_type(8))) short short8;
typedef __attribute__((ext_vector_type(4))) float f32x4;

static __device__ __forceinline__ float silu_f(float x) {
  return x / (1.0f + expf(-x));
}
static __device__ __forceinline__ ushort f2bf(float x) {
  unsigned u = __float_as_uint(x);
  unsigned r = (u + 0x7FFFu + ((u >> 16) & 1u)) >> 16;
  return (ushort)r;
}
static __device__ __forceinline__ float bf2f(ushort h) {
  return __uint_as_float(((unsigned)h) << 16);
}

// ---------------- setup: rbf table + in-degree ----------------
__global__ __launch_bounds__(256) void k_setup(
    const float* __restrict__ edge_d, const int* __restrict__ tgt,
    float* __restrict__ rbfE, float* __restrict__ cnt)
{
  int e = blockIdx.x * 256 + threadIdx.x;
  if (e >= NE) return;
  float d = edge_d[e];
  float env = 0.0f;
  if (d < 5.0f) env = 0.5f * cosf(d * 0.628318530717958648f) + 0.5f; // pi/5
  #pragma unroll
  for (int j = 0; j < 20; ++j) {
    float mu = (5.0f / 19.0f) * (float)j;     // linspace(0,5,20)
    float x = d - mu;
    rbfE[e * 20 + j] = env * expf(-8.0f * x * x); // coeff = -0.5/(0.25^2)
  }
  atomicAdd(&cnt[tgt[e]], 1.0f);
}

__global__ __launch_bounds__(256) void k_invcnt(
    const float* __restrict__ cnt, float* __restrict__ icnt)
{
  int n = blockIdx.x * 256 + threadIdx.x;
  if (n < NN) icnt[n] = 1.0f / fmaxf(cnt[n], 1.0f);
}

// ---------------- exclusive scan of cnt -> rowstart (single block) ----------------
__global__ __launch_bounds__(256) void k_scan(
    const float* __restrict__ cnt, int* __restrict__ rowstart)
{
  __shared__ float buf[256];
  __shared__ float carry_s;
  int tid = threadIdx.x;
  if (tid == 0) carry_s = 0.0f;
  __syncthreads();
  for (int base = 0; base < NN; base += 256) {
    int i = base + tid;
    float c = (i < NN) ? cnt[i] : 0.0f;
    buf[tid] = c;
    __syncthreads();
    for (int off = 1; off < 256; off <<= 1) {
      float v = (tid >= off) ? buf[tid - off] : 0.0f;
      __syncthreads();
      buf[tid] += v;
      __syncthreads();
    }
    float incl = buf[tid];
    float carry = carry_s;
    if (i < NN) rowstart[i] = (int)(carry + incl - c);
    __syncthreads();
    if (tid == 255) carry_s = carry + buf[255];
    __syncthreads();
  }
  if (tid == 0) rowstart[NN] = NE;
}

// ---------------- place edges into sorted-by-target order ----------------
__global__ __launch_bounds__(256) void k_place(
    const int* __restrict__ src, const int* __restrict__ tgt,
    const float* __restrict__ rnorm,
    const int* __restrict__ rowstart, int* __restrict__ fill,
    int* __restrict__ eperm, int* __restrict__ src_s, int* __restrict__ tgt_s,
    float* __restrict__ rn_s)
{
  int e = blockIdx.x * 256 + threadIdx.x;
  if (e >= NE) return;
  int t = tgt[e];
  int pos = rowstart[t] + atomicAdd(&fill[t], 1);
  eperm[pos] = e;
  src_s[pos] = src[e];
  tgt_s[pos] = t;
  rn_s[pos * 4 + 0] = rnorm[(size_t)e * 3 + 0];
  rn_s[pos * 4 + 1] = rnorm[(size_t)e * 3 + 1];
  rn_s[pos * 4 + 2] = rnorm[(size_t)e * 3 + 2];
  rn_s[pos * 4 + 3] = 0.0f;
}

// ---------------- split-transpose We2 cols 256..511 -> Wg_hi/lo [n][k] bf16 ----------------
__global__ __launch_bounds__(256) void k_w2bf(
    const float* __restrict__ W2,       // [256][512]
    ushort* __restrict__ wg_hi, ushort* __restrict__ wg_lo)
{
  int n = blockIdx.x, k = threadIdx.x;  // 256 x 256
  float x = W2[(size_t)k * 512 + 256 + n];
  ushort hb = f2bf(x);
  wg_hi[n * 256 + k] = hb;
  wg_lo[n * 256 + k] = f2bf(x - bf2f(hb));
}

// ---------------- LayerNorm(s) + vnorm(v), with optional copies ----------------
__global__ __launch_bounds__(256) void k_ln_vnorm(
    const float* __restrict__ s, const float* __restrict__ v,
    const float* __restrict__ gamma, const float* __restrict__ beta,
    float* __restrict__ s_ln, float* __restrict__ s_copy,
    float* __restrict__ v_n, float* __restrict__ v_copy)
{
  int n = blockIdx.x, t = threadIdx.x;
  __shared__ float red[8];
  float x = s[n * SD + t];
  float ss = x, sq = x * x;
  #pragma unroll
  for (int o = 32; o > 0; o >>= 1) { ss += __shfl_down(ss, o); sq += __shfl_down(sq, o); }
  int wid = t >> 6;
  if ((t & 63) == 0) { red[wid * 2] = ss; red[wid * 2 + 1] = sq; }
  __syncthreads();
  if (t == 0) {
    float S = red[0] + red[2] + red[4] + red[6];
    float Q = red[1] + red[3] + red[5] + red[7];
    float mu = S * (1.0f / SD);
    float var = Q * (1.0f / SD) - mu * mu;
    red[0] = mu; red[1] = rsqrtf(var + 1e-6f);
  }
  __syncthreads();
  float mu = red[0], rstd = red[1];
  float y = (x - mu) * rstd * gamma[t] + beta[t];
  s_ln[n * SD + t] = y;
  if (s_copy) s_copy[n * SD + t] = y;
  __syncthreads();
  float v0 = v[n * 384 + t];
  float v1 = (t < 128) ? v[n * 384 + 256 + t] : 0.0f;
  float q = v0 * v0 + v1 * v1;
  #pragma unroll
  for (int o = 32; o > 0; o >>= 1) q += __shfl_down(q, o);
  if ((t & 63) == 0) red[wid] = q;
  __syncthreads();
  if (t == 0) red[4] = rsqrtf((red[0] + red[1] + red[2] + red[3]) * (1.0f / VD) + 1e-6f);
  __syncthreads();
  float rf = red[4];
  float w0 = v0 * rf;
  v_n[n * 384 + t] = w0;
  if (v_copy) v_copy[n * 384 + t] = w0;
  if (t < 128) {
    float w1 = v1 * rf;
    v_n[n * 384 + 256 + t] = w1;
    if (v_copy) v_copy[n * 384 + 256 + t] = w1;
  }
}

// ---------------- generic fp32 GEMM: C[M,N] = A[M,K] @ W[K,N] (+bias, +silu) ----------------
template<int DO_SILU>
__global__ __launch_bounds__(256) void k_gemm(
    const float* __restrict__ A, int lda,
    const float* __restrict__ W, int ldw,
    const float* __restrict__ bias,
    float* __restrict__ C, int ldc,
    int M, int K)
{
  __shared__ float As[16][66];
  __shared__ float Ws[16][66];
  int row0 = blockIdx.y * 64, col0 = blockIdx.x * 64;
  int tid = threadIdx.x;
  int tx = tid & 15, ty = tid >> 4;
  float acc[4][4] = {};
  for (int k0 = 0; k0 < K; k0 += 16) {
    __syncthreads();
    {
      int r = tid >> 2, kk0 = (tid & 3) * 4;
      float4 a = make_float4(0.f, 0.f, 0.f, 0.f);
      if (row0 + r < M) a = *(const float4*)&A[(size_t)(row0 + r) * lda + k0 + kk0];
      As[kk0 + 0][r] = a.x; As[kk0 + 1][r] = a.y; As[kk0 + 2][r] = a.z; As[kk0 + 3][r] = a.w;
    }
    {
      int kk = tid >> 4, c0 = (tid & 15) * 4;
      float4 w4 = *(const float4*)&W[(size_t)(k0 + kk) * ldw + col0 + c0];
      Ws[kk][c0 + 0] = w4.x; Ws[kk][c0 + 1] = w4.y; Ws[kk][c0 + 2] = w4.z; Ws[kk][c0 + 3] = w4.w;
    }
    __syncthreads();
    #pragma unroll
    for (int kk = 0; kk < 16; ++kk) {
      float a[4], b[4];
      #pragma unroll
      for (int i = 0; i < 4; ++i) a[i] = As[kk][ty * 4 + i];
      #pragma unroll
      for (int j = 0; j < 4; ++j) b[j] = Ws[kk][tx * 4 + j];
      #pragma unroll
      for (int i = 0; i < 4; ++i)
        #pragma unroll
        for (int j = 0; j < 4; ++j) acc[i][j] += a[i] * b[j];
    }
  }
  #pragma unroll
  for (int i = 0; i < 4; ++i) {
    int r = row0 + ty * 4 + i;
    if (r >= M) continue;
    #pragma unroll
    for (int j = 0; j < 4; ++j) {
      int c = col0 + tx * 4 + j;
      float val = acc[i][j] + (bias ? bias[c] : 0.0f);
      if (DO_SILU) val = silu_f(val);
      C[(size_t)r * ldc + c] = val;
    }
  }
}

// ---------------- s_next += (hsum @ Ws + cnt*bs) * icnt ----------------
__global__ __launch_bounds__(256) void k_snext(
    const float* __restrict__ A,           // hsum [NN,256]
    const float* __restrict__ W, int ldw,  // We2_i (cols 0..255), ldw=512
    const float* __restrict__ bs,          // be2_i[0..255]
    const float* __restrict__ cntf, const float* __restrict__ icnt,
    float* __restrict__ s_next)
{
  __shared__ float As[16][66];
  __shared__ float Ws_[16][66];
  int row0 = blockIdx.y * 64, col0 = blockIdx.x * 64;
  int tid = threadIdx.x;
  int tx = tid & 15, ty = tid >> 4;
  float acc[4][4] = {};
  for (int k0 = 0; k0 < SD; k0 += 16) {
    __syncthreads();
    {
      int r = tid >> 2, kk0 = (tid & 3) * 4;
      float4 a = make_float4(0.f, 0.f, 0.f, 0.f);
      if (row0 + r < NN) a = *(const float4*)&A[(size_t)(row0 + r) * SD + k0 + kk0];
      As[kk0 + 0][r] = a.x; As[kk0 + 1][r] = a.y; As[kk0 + 2][r] = a.z; As[kk0 + 3][r] = a.w;
    }
    {
      int kk = tid >> 4, c0 = (tid & 15) * 4;
      float4 w4 = *(const float4*)&W[(size_t)(k0 + kk) * ldw + col0 + c0];
      Ws_[kk][c0 + 0] = w4.x; Ws_[kk][c0 + 1] = w4.y; Ws_[kk][c0 + 2] = w4.z; Ws_[kk][c0 + 3] = w4.w;
    }
    __syncthreads();
    #pragma unroll
    for (int kk = 0; kk < 16; ++kk) {
      float a[4], b[4];
      #pragma unroll
      for (int i = 0; i < 4; ++i) a[i] = As[kk][ty * 4 + i];
      #pragma unroll
      for (int j = 0; j < 4; ++j) b[j] = Ws_[kk][tx * 4 + j];
      #pragma unroll
      for (int i = 0; i < 4; ++i)
        #pragma unroll
        for (int j = 0; j < 4; ++j) acc[i][j] += a[i] * b[j];
    }
  }
  #pragma unroll
  for (int i = 0; i < 4; ++i) {
    int r = row0 + ty * 4 + i;
    if (r >= NN) continue;
    float cf = cntf[r], ic = icnt[r];
    #pragma unroll
    for (int j = 0; j < 4; ++j) {
      int c = col0 + tx * 4 + j;
      s_next[(size_t)r * SD + c] += (acc[i][j] + cf * bs[c]) * ic;
    }
  }
}

// ---------------- h = silu(pre1[src] + pre2[tgt] + ef@W1c + be1) -> bf16 hi/lo ----------------
__global__ __launch_bounds__(256) void k_h(
    const float* __restrict__ rbfE, const float* __restrict__ edge_a,
    const float* __restrict__ edge_e, const float* __restrict__ edge_ohe,
    const float* __restrict__ edge_g,
    const int* __restrict__ eperm,
    const int* __restrict__ src_s, const int* __restrict__ tgt_s,
    const float* __restrict__ pre12,
    const float* __restrict__ W1c,   // We1 rows 512..599 -> [88][256]
    const float* __restrict__ be1,
    int e0,
    ushort* __restrict__ h_hi, ushort* __restrict__ h_lo)
{
  __shared__ float efs[32][EFD];
  __shared__ float wc[8][SD];
  __shared__ int ep[32];
  int le0 = blockIdx.x * 32;       // chunk-local sorted position
  int ge0 = e0 + le0;              // global sorted position
  int tid = threadIdx.x;
  if (tid < 32) ep[tid] = eperm[ge0 + tid];
  __syncthreads();
  for (int slot = tid; slot < 32 * EFD; slot += 256) {
    int el = slot / EFD, j = slot - el * EFD;
    int e = ep[el];
    float val;
    if (j < 20)       val = rbfE[e * 20 + j];
    else if (j == 20) val = edge_a[e];
    else if (j < 53)  val = edge_e[(size_t)e * 32 + (j - 21)];
    else if (j < 56)  val = edge_ohe[(size_t)e * 3 + (j - 53)];
    else              val = edge_g[(size_t)e * 32 + (j - 56)];
    efs[el][j] = val;
  }
  int cg = tid & 15, er = tid >> 4;
  int pA = ge0 + er * 2, pB = pA + 1;
  float acc0[16] = {}, acc1[16] = {};
  for (int j0 = 0; j0 < EFD; j0 += 8) {
    __syncthreads();
    for (int sl = tid; sl < 8 * SD; sl += 256) {
      int jj = sl >> 8, c = sl & 255;
      wc[jj][c] = W1c[(j0 + jj) * SD + c];
    }
    __syncthreads();
    #pragma unroll
    for (int jj = 0; jj < 8; ++jj) {
      float a0 = efs[er * 2][j0 + jj];
      float a1 = efs[er * 2 + 1][j0 + jj];
      #pragma unroll
      for (int u = 0; u < 16; ++u) {
        float wv = wc[jj][cg + 16 * u];
        acc0[u] += a0 * wv;
        acc1[u] += a1 * wv;
      }
    }
  }
  int sA = src_s[pA], tA = tgt_s[pA], sB = src_s[pB], tB = tgt_s[pB];
  size_t hA = (size_t)(le0 + er * 2) * SD;
  #pragma unroll
  for (int u = 0; u < 16; ++u) {
    int c = cg + 16 * u;
    float b = be1[c];
    float x0 = acc0[u] + pre12[(size_t)sA * 512 + c] + pre12[(size_t)tA * 512 + 256 + c] + b;
    float x1 = acc1[u] + pre12[(size_t)sB * 512 + c] + pre12[(size_t)tB * 512 + 256 + c] + b;
    float s0 = silu_f(x0), s1 = silu_f(x1);
    ushort hb0 = f2bf(s0), hb1 = f2bf(s1);
    h_hi[hA + c]      = hb0;
    h_lo[hA + c]      = f2bf(s0 - bf2f(hb0));
    h_hi[hA + SD + c] = hb1;
    h_lo[hA + SD + c] = f2bf(s1 - bf2f(hb1));
  }
}

// ---------------- g = h @ Wg + bias via split-bf16 MFMA ----------------
// grid (ce/64, 4); 64x64 tile; 4 waves, wave w = rows [16w,16w+16).
// A = h (hi+lo bf16, [ce][256] k-major); B = Wg (hi+lo bf16, [n][k]).
// g ~= Ah*Bh + Ah*Bl + Al*Bh (fp32 acc).
__global__ __launch_bounds__(256) void k_gmfma(
    const ushort* __restrict__ h_hi, const ushort* __restrict__ h_lo,
    const ushort* __restrict__ wg_hi, const ushort* __restrict__ wg_lo,
    const float* __restrict__ bias,   // 256 entries (be2[256:512])
    float* __restrict__ g, int ce)
{
  __shared__ __align__(16) ushort Ah[64 * 40];
  __shared__ __align__(16) ushort Al[64 * 40];
  __shared__ __align__(16) ushort Bh[64 * 40];
  __shared__ __align__(16) ushort Bl[64 * 40];
  int m0 = blockIdx.x * 64;
  int n0 = blockIdx.y * 64;
  int tid = threadIdx.x;
  int srow = tid >> 2, sk8 = (tid & 3) * 8;   // staging: 4 threads/row
  int lane = tid & 63, wv = tid >> 6;
  int lg = lane >> 4, lm = lane & 15;
  f32x4 acc[4] = {};
  for (int k0 = 0; k0 < 256; k0 += 32) {
    __syncthreads();
    *(uint4*)&Ah[srow * 40 + sk8] = *(const uint4*)&h_hi[(size_t)(m0 + srow) * 256 + k0 + sk8];
    *(uint4*)&Al[srow * 40 + sk8] = *(const uint4*)&h_lo[(size_t)(m0 + srow) * 256 + k0 + sk8];
    *(uint4*)&Bh[srow * 40 + sk8] = *(const uint4*)&wg_hi[(size_t)(n0 + srow) * 256 + k0 + sk8];
    *(uint4*)&Bl[srow * 40 + sk8] = *(const uint4*)&wg_lo[(size_t)(n0 + srow) * 256 + k0 + sk8];
    __syncthreads();
    short8 ah = *(const short8*)&Ah[(16 * wv + lm) * 40 + 8 * lg];
    short8 al = *(const short8*)&Al[(16 * wv + lm) * 40 + 8 * lg];
    #pragma unroll
    for (int cf = 0; cf < 4; ++cf) {
      short8 bh = *(const short8*)&Bh[(16 * cf + lm) * 40 + 8 * lg];
      short8 bl = *(const short8*)&Bl[(16 * cf + lm) * 40 + 8 * lg];
      acc[cf] = __builtin_amdgcn_mfma_f32_16x16x32_bf16(ah, bh, acc[cf], 0, 0, 0);
      acc[cf] = __builtin_amdgcn_mfma_f32_16x16x32_bf16(ah, bl, acc[cf], 0, 0, 0);
      acc[cf] = __builtin_amdgcn_mfma_f32_16x16x32_bf16(al, bh, acc[cf], 0, 0, 0);
    }
  }
  (void)ce;
  #pragma unroll
  for (int cf = 0; cf < 4; ++cf) {
    int col = n0 + 16 * cf + lm;
    float b = bias[col];
    #pragma unroll
    for (int r = 0; r < 4; ++r) {
      int row = m0 + 16 * wv + 4 * lg + r;
      g[(size_t)row * 256 + col] = acc[cf][r] + b;
    }
  }
}

// ---------------- per-node contiguous gather (no atomics) ----------------
__global__ __launch_bounds__(256) void k_gather(
    const ushort* __restrict__ h_hi, const ushort* __restrict__ h_lo,
    const float* __restrict__ g,      // [ce,256] chunk-local: gr|gv (bias incl)
    const int* __restrict__ rowstart,
    const int* __restrict__ src_s,
    const float* __restrict__ rn_s,
    const float* __restrict__ v_n,
    const float* __restrict__ icnt,
    int e0, int ce,
    float* __restrict__ hsum, float* __restrict__ v_next)
{
  int t = blockIdx.x;
  int lo = rowstart[t], hi = rowstart[t + 1];
  if (lo < e0) lo = e0;
  int e1 = e0 + ce;
  if (hi > e1) hi = e1;
  if (lo >= hi) return;
  int tid = threadIdx.x;
  int k = tid & 127, half = tid >> 7;
  float hacc = 0.0f, a0 = 0.0f, a1 = 0.0f, a2 = 0.0f;
  for (int p = lo; p < hi; ++p) {
    int lp = p - e0;
    hacc += bf2f(h_hi[(size_t)lp * SD + tid]) + bf2f(h_lo[(size_t)lp * SD + tid]);
    float gr = g[(size_t)lp * SD + k];
    float gv = g[(size_t)lp * SD + 128 + k];
    int sn = src_s[p];
    const float* vs = &v_n[(size_t)sn * 384];
    if (half == 0) {
      float r0 = rn_s[(size_t)p * 4 + 0];
      float r2 = rn_s[(size_t)p * 4 + 2];
      a0 += gr * r0 + gv * vs[k];
      a2 += gr * r2 + gv * vs[256 + k];
    } else {
      float r1 = rn_s[(size_t)p * 4 + 1];
      a1 += gr * r1 + gv * vs[128 + k];
    }
  }
  hsum[(size_t)t * SD + tid] += hacc;
  float ic = icnt[t];
  if (half == 0) {
    v_next[(size_t)t * 384 + k]       += ic * a0;
    v_next[(size_t)t * 384 + 256 + k] += ic * a2;
  } else {
    v_next[(size_t)t * 384 + 128 + k] += ic * a1;
  }
}

// ---------------- nv = sqrt(sum_c vv^2 + eps); xcat = [s | nv] ----------------
__global__ __launch_bounds__(256) void k_nv_xcat(
    const float* __restrict__ vv, const float* __restrict__ s_next,
    float* __restrict__ xcat)
{
  int n = blockIdx.x, t = threadIdx.x;
  xcat[(size_t)n * 384 + t] = s_next[(size_t)n * SD + t];
  if (t < 128) {
    float a = vv[(size_t)(n * 3 + 0) * VD + t];
    float b = vv[(size_t)(n * 3 + 1) * VD + t];
    float c = vv[(size_t)(n * 3 + 2) * VD + t];
    xcat[(size_t)n * 384 + 256 + t] = sqrtf(a * a + b * b + c * c + 1e-6f);
  }
}

// ---------------- s_cur = s_next + u[:, :256]; v_cur = v_next + vv * u[:, None, 256:] ----------------
__global__ __launch_bounds__(256) void k_update(
    const float* __restrict__ s_next, const float* __restrict__ v_next,
    const float* __restrict__ vv, const float* __restrict__ u,
    float* __restrict__ s_cur, float* __restrict__ v_cur)
{
  int i = blockIdx.x * 256 + threadIdx.x;
  const int NVT = NN * 384;
  if (i < NVT) {
    int n = i / 384;
    int k = (i - n * 384) & 127;
    v_cur[i] = v_next[i] + vv[i] * u[(size_t)n * 384 + 256 + k];
  } else {
    int j = i - NVT;
    if (j < NN * SD) {
      int n = j >> 8, c = j & 255;
      s_cur[j] = s_next[j] + u[(size_t)n * 384 + c];
    }
  }
}

// =====================================================================
extern "C" void kernel_launch(void* const* d_in, const int* in_sizes, int n_in,
                              void* d_out, int out_size, void* d_ws, size_t ws_size,
                              hipStream_t stream)
{
  const float* s_in   = (const float*)d_in[0];
  const float* v_in   = (const float*)d_in[1];
  const float* p_in   = (const float*)d_in[2];
  const int*   eidx   = (const int*)d_in[3];
  const float* edge_d = (const float*)d_in[4];
  const float* edge_a = (const float*)d_in[5];
  const float* rnorm  = (const float*)d_in[6];
  const float* edge_e = (const float*)d_in[7];
  const float* edge_o = (const float*)d_in[8];
  const float* edge_g = (const float*)d_in[9];
  const float* gamma  = (const float*)d_in[10];
  const float* beta   = (const float*)d_in[11];
  const float* We1    = (const float*)d_in[12];
  const float* be1    = (const float*)d_in[13];
  const float* We2    = (const float*)d_in[14];
  const float* be2    = (const float*)d_in[15];
  const float* Wvu    = (const float*)d_in[16];
  const float* Wu1    = (const float*)d_in[17];
  const float* bu1    = (const float*)d_in[18];
  const float* Wu2    = (const float*)d_in[19];
  const float* bu2    = (const float*)d_in[20];
  const int* srcA = eidx;
  const int* tgtA = eidx + NE;

  float* w = (float*)d_ws;
  float* s_cur  = w; w += NN * SD;
  float* v_cur  = w; w += NN * 384;
  float* s_ln   = w; w += NN * SD;      // reused later as tbuf
  float* v_nrm  = w; w += NN * 384;     // reused later as ubuf
  float* s_next = w; w += NN * SD;
  float* v_next = w; w += NN * 384;
  float* pre12  = w; w += NN * 512;     // reused later as xcat (N*384)
  float* rbfE   = w; w += (size_t)NE * 20;
  float* cnt    = w; w += NN;
  float* icnt   = w; w += NN;
  float* vv     = w; w += NN * 384;
  float* hsum   = w; w += NN * SD;
  ushort* wg_hi = (ushort*)w; w += 32768;   // 256*256 bf16
  ushort* wg_lo = (ushort*)w; w += 32768;
  int*   rowstart = (int*)w; w += NN + 4;   // padded to keep 16B alignment
  int*   fill     = (int*)w; w += NN;
  int*   eperm    = (int*)w; w += NE;
  int*   src_s    = (int*)w; w += NE;
  int*   tgt_s    = (int*)w; w += NE;
  float* rn_s   = w; w += (size_t)NE * 4;
  float* tbuf = s_ln;
  float* ubuf = v_nrm;
  float* xcat = pre12;

  // chunking: per chunk need chunkE*256 ushort (h_hi) + same (h_lo) + chunkE*256
  // float (g) = chunkE*512 floats total in the remainder
  size_t fixedF = (size_t)(w - (float*)d_ws);
  size_t totalF = ws_size / sizeof(float);
  size_t availF = (totalF > fixedF) ? (totalF - fixedF) : 0;
  long long mc = (long long)(availF / 512) & ~127LL;   // multiple of 128 edges
  if (mc > NE) mc = NE;
  if (mc < 128) mc = 128;
  const int chunkE = (int)mc;
  ushort* h_hi = (ushort*)w;
  ushort* h_lo = h_hi + (size_t)chunkE * SD;
  float*  gbuf = (float*)(h_lo + (size_t)chunkE * SD);

  hipMemsetAsync(cnt, 0, NN * sizeof(float), stream);
  hipMemsetAsync(fill, 0, NN * sizeof(int), stream);
  k_setup<<<(NE + 255) / 256, 256, 0, stream>>>(edge_d, tgtA, rbfE, cnt);
  k_scan<<<1, 256, 0, stream>>>(cnt, rowstart);
  k_invcnt<<<(NN + 255) / 256, 256, 0, stream>>>(cnt, icnt);
  k_place<<<(NE + 255) / 256, 256, 0, stream>>>(srcA, tgtA, rnorm, rowstart, fill,
                                                eperm, src_s, tgt_s, rn_s);

  const float* sp = s_in;
  const float* vp = v_in;
  for (int i = 0; i < 5; ++i) {
    k_ln_vnorm<<<NN, 256, 0, stream>>>(sp, vp, gamma + i * SD, beta + i * SD,
                                       s_ln, s_next, v_nrm, v_next);
    const float* W1 = We1 + (size_t)i * DIN_ * SD;
    const float* W2 = We2 + (size_t)i * SD * 512;
    k_w2bf<<<256, 256, 0, stream>>>(W2, wg_hi, wg_lo);
    // pre1 (s[src] part) and pre2 (s[tgt] part), stored side by side [N,512]
    k_gemm<0><<<dim3(4, 157), 256, 0, stream>>>(s_ln, SD, W1, SD, nullptr,
                                                pre12, 512, NN, SD);
    k_gemm<0><<<dim3(4, 157), 256, 0, stream>>>(s_ln, SD, W1 + 256 * SD, SD, nullptr,
                                                pre12 + 256, 512, NN, SD);
    hipMemsetAsync(hsum, 0, (size_t)NN * SD * sizeof(float), stream);
    for (int e0 = 0; e0 < NE; e0 += chunkE) {
      int ce = NE - e0; if (ce > chunkE) ce = chunkE;
      k_h<<<ce / 32, 256, 0, stream>>>(rbfE, edge_a, edge_e, edge_o, edge_g,
                                       eperm, src_s, tgt_s, pre12, W1 + 512 * SD,
                                       be1 + i * SD, e0, h_hi, h_lo);
      // g = h @ We2[:,256:512] + be2[256:512]   (gr | gv), split-bf16 MFMA
      k_gmfma<<<dim3(ce / 64, 4), 256, 0, stream>>>(h_hi, h_lo, wg_hi, wg_lo,
                                                    be2 + i * 512 + 256, gbuf, ce);
      k_gather<<<NN, 256, 0, stream>>>(h_hi, h_lo, gbuf, rowstart, src_s, rn_s,
                                       v_nrm, icnt, e0, ce, hsum, v_next);
    }
    // s_next += (hsum @ We2[:,0:256] + cnt*be2[0:256]) * icnt
    k_snext<<<dim3(4, 157), 256, 0, stream>>>(hsum, W2, 512, be2 + i * 512,
                                              cnt, icnt, s_next);
    if (i < 4) {
      k_gemm<0><<<dim3(2, 469), 256, 0, stream>>>(v_next, VD, Wvu + i * VD * VD, VD,
                                                  nullptr, vv, VD, 3 * NN, VD);
      k_nv_xcat<<<NN, 256, 0, stream>>>(vv, s_next, xcat);
      k_gemm<1><<<dim3(4, 157), 256, 0, stream>>>(xcat, 384, Wu1 + (size_t)i * 384 * SD, SD,
                                                  bu1 + i * SD, tbuf, SD, NN, 384);
      k_gemm<0><<<dim3(6, 157), 256, 0, stream>>>(tbuf, SD, Wu2 + (size_t)i * SD * 384, 384,
                                                  bu2 + i * 384, ubuf, 384, NN, SD);
      k_update<<<(NN * 640 + 255) / 256, 256, 0, stream>>>(s_next, v_next, vv, ubuf,
                                                           s_cur, v_cur);
      sp = s_cur; vp = v_cur;
    }
  }
  float* out = (float*)d_out;
  k_ln_vnorm<<<NN, 256, 0, stream>>>(s_next, v_next, gamma + 5 * SD, beta + 5 * SD,
                                     out, nullptr, out + NN * SD, nullptr);
  float* outp = out + (size_t)NN * SD + (size_t)NN * 384;
  hipMemcpyAsync(outp, p_in, NN * 3 * sizeof(float), hipMemcpyDeviceToDevice, stream);
  hipMemcpyAsync(outp + NN * 3, edge_e, (size_t)NE * 32 * sizeof(float),
                 hipMemcpyDeviceToDevice, stream);
}

// Round 10
// 3435.057 us; speedup vs baseline: 3.7192x; 1.3255x over previous
//
#include <hip/hip_runtime.h>
#include <math.h>

// EQGAT edge GNN — round 10: BN=256 g-GEMM (kills 4x h over-fetch) and all
// node GEMMs converted to the HW-validated split-bf16 MFMA pattern.

constexpr int NN  = 10000;   // nodes
constexpr int NE  = 160000;  // edges
constexpr int SD  = 256;     // SDIM
constexpr int VD  = 128;     // VDIM
constexpr int EFD = 88;      // rbf(20)+a(1)+e(32)+ohe(3)+g(32)
constexpr int DIN_ = 600;

typedef __attribute__((ext_vector_type(8))) short short8;
typedef __attribute__((ext_vector_type(4))) float f32x4;

static __device__ __forceinline__ float silu_f(float x) {
  return x / (1.0f + expf(-x));
}
static __device__ __forceinline__ ushort f2bf(float x) {
  unsigned u = __float_as_uint(x);
  unsigned r = (u + 0x7FFFu + ((u >> 16) & 1u)) >> 16;
  return (ushort)r;
}
static __device__ __forceinline__ float bf2f(ushort h) {
  return __uint_as_float(((unsigned)h) << 16);
}

// ---------------- setup: rbf table + in-degree ----------------
__global__ __launch_bounds__(256) void k_setup(
    const float* __restrict__ edge_d, const int* __restrict__ tgt,
    float* __restrict__ rbfE, float* __restrict__ cnt)
{
  int e = blockIdx.x * 256 + threadIdx.x;
  if (e >= NE) return;
  float d = edge_d[e];
  float env = 0.0f;
  if (d < 5.0f) env = 0.5f * cosf(d * 0.628318530717958648f) + 0.5f; // pi/5
  #pragma unroll
  for (int j = 0; j < 20; ++j) {
    float mu = (5.0f / 19.0f) * (float)j;     // linspace(0,5,20)
    float x = d - mu;
    rbfE[e * 20 + j] = env * expf(-8.0f * x * x); // coeff = -0.5/(0.25^2)
  }
  atomicAdd(&cnt[tgt[e]], 1.0f);
}

__global__ __launch_bounds__(256) void k_invcnt(
    const float* __restrict__ cnt, float* __restrict__ icnt)
{
  int n = blockIdx.x * 256 + threadIdx.x;
  if (n < NN) icnt[n] = 1.0f / fmaxf(cnt[n], 1.0f);
}

// ---------------- exclusive scan of cnt -> rowstart (single block) ----------------
__global__ __launch_bounds__(256) void k_scan(
    const float* __restrict__ cnt, int* __restrict__ rowstart)
{
  __shared__ float buf[256];
  __shared__ float carry_s;
  int tid = threadIdx.x;
  if (tid == 0) carry_s = 0.0f;
  __syncthreads();
  for (int base = 0; base < NN; base += 256) {
    int i = base + tid;
    float c = (i < NN) ? cnt[i] : 0.0f;
    buf[tid] = c;
    __syncthreads();
    for (int off = 1; off < 256; off <<= 1) {
      float v = (tid >= off) ? buf[tid - off] : 0.0f;
      __syncthreads();
      buf[tid] += v;
      __syncthreads();
    }
    float incl = buf[tid];
    float carry = carry_s;
    if (i < NN) rowstart[i] = (int)(carry + incl - c);
    __syncthreads();
    if (tid == 255) carry_s = carry + buf[255];
    __syncthreads();
  }
  if (tid == 0) rowstart[NN] = NE;
}

// ---------------- place edges into sorted-by-target order ----------------
__global__ __launch_bounds__(256) void k_place(
    const int* __restrict__ src, const int* __restrict__ tgt,
    const float* __restrict__ rnorm,
    const int* __restrict__ rowstart, int* __restrict__ fill,
    int* __restrict__ eperm, int* __restrict__ src_s, int* __restrict__ tgt_s,
    float* __restrict__ rn_s)
{
  int e = blockIdx.x * 256 + threadIdx.x;
  if (e >= NE) return;
  int t = tgt[e];
  int pos = rowstart[t] + atomicAdd(&fill[t], 1);
  eperm[pos] = e;
  src_s[pos] = src[e];
  tgt_s[pos] = t;
  rn_s[pos * 4 + 0] = rnorm[(size_t)e * 3 + 0];
  rn_s[pos * 4 + 1] = rnorm[(size_t)e * 3 + 1];
  rn_s[pos * 4 + 2] = rnorm[(size_t)e * 3 + 2];
  rn_s[pos * 4 + 3] = 0.0f;
}

// ---------------- split-transpose We2 cols 256..511 -> Wg_hi/lo [n][k] bf16 ----------------
__global__ __launch_bounds__(256) void k_w2bf(
    const float* __restrict__ W2,       // [256][512]
    ushort* __restrict__ wg_hi, ushort* __restrict__ wg_lo)
{
  int n = blockIdx.x, k = threadIdx.x;  // 256 x 256
  float x = W2[(size_t)k * 512 + 256 + n];
  ushort hb = f2bf(x);
  wg_hi[n * 256 + k] = hb;
  wg_lo[n * 256 + k] = f2bf(x - bf2f(hb));
}

// ---------------- generic split-transpose W[K][ldw] col n -> wt[nbase+n][K] ----------------
__global__ __launch_bounds__(256) void k_wsplit(
    const float* __restrict__ W, int ldw, int K, int nbase,
    ushort* __restrict__ whi, ushort* __restrict__ wlo)
{
  int n = blockIdx.x;
  for (int k = threadIdx.x; k < K; k += 256) {
    float x = W[(size_t)k * ldw + n];
    ushort hb = f2bf(x);
    whi[(size_t)(nbase + n) * K + k] = hb;
    wlo[(size_t)(nbase + n) * K + k] = f2bf(x - bf2f(hb));
  }
}

// ---------------- LayerNorm(s) + vnorm(v), with optional copies ----------------
__global__ __launch_bounds__(256) void k_ln_vnorm(
    const float* __restrict__ s, const float* __restrict__ v,
    const float* __restrict__ gamma, const float* __restrict__ beta,
    float* __restrict__ s_ln, float* __restrict__ s_copy,
    float* __restrict__ v_n, float* __restrict__ v_copy)
{
  int n = blockIdx.x, t = threadIdx.x;
  __shared__ float red[8];
  float x = s[n * SD + t];
  float ss = x, sq = x * x;
  #pragma unroll
  for (int o = 32; o > 0; o >>= 1) { ss += __shfl_down(ss, o); sq += __shfl_down(sq, o); }
  int wid = t >> 6;
  if ((t & 63) == 0) { red[wid * 2] = ss; red[wid * 2 + 1] = sq; }
  __syncthreads();
  if (t == 0) {
    float S = red[0] + red[2] + red[4] + red[6];
    float Q = red[1] + red[3] + red[5] + red[7];
    float mu = S * (1.0f / SD);
    float var = Q * (1.0f / SD) - mu * mu;
    red[0] = mu; red[1] = rsqrtf(var + 1e-6f);
  }
  __syncthreads();
  float mu = red[0], rstd = red[1];
  float y = (x - mu) * rstd * gamma[t] + beta[t];
  s_ln[n * SD + t] = y;
  if (s_copy) s_copy[n * SD + t] = y;
  __syncthreads();
  float v0 = v[n * 384 + t];
  float v1 = (t < 128) ? v[n * 384 + 256 + t] : 0.0f;
  float q = v0 * v0 + v1 * v1;
  #pragma unroll
  for (int o = 32; o > 0; o >>= 1) q += __shfl_down(q, o);
  if ((t & 63) == 0) red[wid] = q;
  __syncthreads();
  if (t == 0) red[4] = rsqrtf((red[0] + red[1] + red[2] + red[3]) * (1.0f / VD) + 1e-6f);
  __syncthreads();
  float rf = red[4];
  float w0 = v0 * rf;
  v_n[n * 384 + t] = w0;
  if (v_copy) v_copy[n * 384 + t] = w0;
  if (t < 128) {
    float w1 = v1 * rf;
    v_n[n * 384 + 256 + t] = w1;
    if (v_copy) v_copy[n * 384 + 256 + t] = w1;
  }
}

// ---------------- generic MFMA GEMM: C[M,N] = op(A[M,K]fp32 @ wt[n][k]) ----------------
// 64x64 tile, 4 waves (wave wv = rows 16wv..+16), split-bf16 3-term.
// grid: (N/64, ceil(M/64)). A split to hi/lo during LDS staging.
// SNEXT=1: C += (acc + cntf[row]*bias[col]) * icnt[row]  (s_next path)
// else:    C  = silu?(acc + bias[col])
template<int DO_SILU, int SNEXT>
__global__ __launch_bounds__(256) void k_gemm_mf(
    const float* __restrict__ A, int lda,
    const ushort* __restrict__ wt_hi, const ushort* __restrict__ wt_lo,
    const float* __restrict__ bias,
    const float* __restrict__ cntf, const float* __restrict__ icnt,
    float* __restrict__ C, int ldc, int M, int K)
{
  __shared__ __align__(16) ushort Ah[64 * 40];
  __shared__ __align__(16) ushort Al[64 * 40];
  __shared__ __align__(16) ushort Bh[64 * 40];
  __shared__ __align__(16) ushort Bl[64 * 40];
  int n0 = blockIdx.x * 64;
  int m0 = blockIdx.y * 64;
  int tid = threadIdx.x;
  int srow = tid >> 2, sk8 = (tid & 3) * 8;
  int lane = tid & 63, wv = tid >> 6;
  int lg = lane >> 4, lm = lane & 15;
  f32x4 acc[4] = {};
  for (int k0 = 0; k0 < K; k0 += 32) {
    __syncthreads();
    {   // A: 64 rows x 32 k fp32 -> hi/lo bf16
      float4 a0 = make_float4(0.f, 0.f, 0.f, 0.f), a1 = a0;
      if (m0 + srow < M) {
        const float4* ap = (const float4*)&A[(size_t)(m0 + srow) * lda + k0 + sk8];
        a0 = ap[0]; a1 = ap[1];
      }
      ushort hi[8], lo[8];
      float af[8] = {a0.x, a0.y, a0.z, a0.w, a1.x, a1.y, a1.z, a1.w};
      #pragma unroll
      for (int j = 0; j < 8; ++j) {
        hi[j] = f2bf(af[j]);
        lo[j] = f2bf(af[j] - bf2f(hi[j]));
      }
      *(uint4*)&Ah[srow * 40 + sk8] = *(const uint4*)hi;
      *(uint4*)&Al[srow * 40 + sk8] = *(const uint4*)lo;
    }
    {   // B: 64 n-rows x 32 k (already bf16 hi/lo)
      *(uint4*)&Bh[srow * 40 + sk8] = *(const uint4*)&wt_hi[(size_t)(n0 + srow) * K + k0 + sk8];
      *(uint4*)&Bl[srow * 40 + sk8] = *(const uint4*)&wt_lo[(size_t)(n0 + srow) * K + k0 + sk8];
    }
    __syncthreads();
    short8 ah = *(const short8*)&Ah[(16 * wv + lm) * 40 + 8 * lg];
    short8 al = *(const short8*)&Al[(16 * wv + lm) * 40 + 8 * lg];
    #pragma unroll
    for (int cf = 0; cf < 4; ++cf) {
      short8 bh = *(const short8*)&Bh[(16 * cf + lm) * 40 + 8 * lg];
      short8 bl = *(const short8*)&Bl[(16 * cf + lm) * 40 + 8 * lg];
      acc[cf] = __builtin_amdgcn_mfma_f32_16x16x32_bf16(ah, bh, acc[cf], 0, 0, 0);
      acc[cf] = __builtin_amdgcn_mfma_f32_16x16x32_bf16(ah, bl, acc[cf], 0, 0, 0);
      acc[cf] = __builtin_amdgcn_mfma_f32_16x16x32_bf16(al, bh, acc[cf], 0, 0, 0);
    }
  }
  #pragma unroll
  for (int cf = 0; cf < 4; ++cf) {
    int col = n0 + 16 * cf + lm;
    float b = bias ? bias[col] : 0.0f;
    #pragma unroll
    for (int r = 0; r < 4; ++r) {
      int row = m0 + 16 * wv + 4 * lg + r;
      if (row >= M) continue;
      if (SNEXT) {
        C[(size_t)row * ldc + col] += (acc[cf][r] + cntf[row] * b) * icnt[row];
      } else {
        float val = acc[cf][r] + b;
        if (DO_SILU) val = silu_f(val);
        C[(size_t)row * ldc + col] = val;
      }
    }
  }
}

// ---------------- h = silu(pre1[src] + pre2[tgt] + ef@W1c + be1) -> bf16 hi/lo ----------------
__global__ __launch_bounds__(256) void k_h(
    const float* __restrict__ rbfE, const float* __restrict__ edge_a,
    const float* __restrict__ edge_e, const float* __restrict__ edge_ohe,
    const float* __restrict__ edge_g,
    const int* __restrict__ eperm,
    const int* __restrict__ src_s, const int* __restrict__ tgt_s,
    const float* __restrict__ pre12,
    const float* __restrict__ W1c,   // We1 rows 512..599 -> [88][256]
    const float* __restrict__ be1,
    int e0,
    ushort* __restrict__ h_hi, ushort* __restrict__ h_lo)
{
  __shared__ float efs[32][EFD];
  __shared__ float wc[8][SD];
  __shared__ int ep[32];
  int le0 = blockIdx.x * 32;       // chunk-local sorted position
  int ge0 = e0 + le0;              // global sorted position
  int tid = threadIdx.x;
  if (tid < 32) ep[tid] = eperm[ge0 + tid];
  __syncthreads();
  for (int slot = tid; slot < 32 * EFD; slot += 256) {
    int el = slot / EFD, j = slot - el * EFD;
    int e = ep[el];
    float val;
    if (j < 20)       val = rbfE[e * 20 + j];
    else if (j == 20) val = edge_a[e];
    else if (j < 53)  val = edge_e[(size_t)e * 32 + (j - 21)];
    else if (j < 56)  val = edge_ohe[(size_t)e * 3 + (j - 53)];
    else              val = edge_g[(size_t)e * 32 + (j - 56)];
    efs[el][j] = val;
  }
  int cg = tid & 15, er = tid >> 4;
  int pA = ge0 + er * 2, pB = pA + 1;
  float acc0[16] = {}, acc1[16] = {};
  for (int j0 = 0; j0 < EFD; j0 += 8) {
    __syncthreads();
    for (int sl = tid; sl < 8 * SD; sl += 256) {
      int jj = sl >> 8, c = sl & 255;
      wc[jj][c] = W1c[(j0 + jj) * SD + c];
    }
    __syncthreads();
    #pragma unroll
    for (int jj = 0; jj < 8; ++jj) {
      float a0 = efs[er * 2][j0 + jj];
      float a1 = efs[er * 2 + 1][j0 + jj];
      #pragma unroll
      for (int u = 0; u < 16; ++u) {
        float wv = wc[jj][cg + 16 * u];
        acc0[u] += a0 * wv;
        acc1[u] += a1 * wv;
      }
    }
  }
  int sA = src_s[pA], tA = tgt_s[pA], sB = src_s[pB], tB = tgt_s[pB];
  size_t hA = (size_t)(le0 + er * 2) * SD;
  #pragma unroll
  for (int u = 0; u < 16; ++u) {
    int c = cg + 16 * u;
    float b = be1[c];
    float x0 = acc0[u] + pre12[(size_t)sA * 512 + c] + pre12[(size_t)tA * 512 + 256 + c] + b;
    float x1 = acc1[u] + pre12[(size_t)sB * 512 + c] + pre12[(size_t)tB * 512 + 256 + c] + b;
    float s0 = silu_f(x0), s1 = silu_f(x1);
    ushort hb0 = f2bf(s0), hb1 = f2bf(s1);
    h_hi[hA + c]      = hb0;
    h_lo[hA + c]      = f2bf(s0 - bf2f(hb0));
    h_hi[hA + SD + c] = hb1;
    h_lo[hA + SD + c] = f2bf(s1 - bf2f(hb1));
  }
}

// ---------------- g = h @ Wg + bias via split-bf16 MFMA, BN=256 ----------------
// grid (ce/64); each block: 64 rows x ALL 256 cols (h fetched once).
// 4 waves; wave wv owns col-slice [64wv, 64wv+64): 4 m-frags x 4 n-frags.
__global__ __launch_bounds__(256) void k_gmfma(
    const ushort* __restrict__ h_hi, const ushort* __restrict__ h_lo,
    const ushort* __restrict__ wg_hi, const ushort* __restrict__ wg_lo,
    const float* __restrict__ bias,   // 256 entries (be2[256:512])
    float* __restrict__ g)
{
  __shared__ __align__(16) ushort Ah[64 * 40];
  __shared__ __align__(16) ushort Al[64 * 40];
  __shared__ __align__(16) ushort Bh[256 * 40];
  __shared__ __align__(16) ushort Bl[256 * 40];
  int m0 = blockIdx.x * 64;
  int tid = threadIdx.x;
  int srow = tid >> 2, sk8 = (tid & 3) * 8;
  int lane = tid & 63, wv = tid >> 6;
  int lg = lane >> 4, lm = lane & 15;
  f32x4 acc[4][4] = {};   // [m-frag][n-frag]
  for (int k0 = 0; k0 < 256; k0 += 32) {
    __syncthreads();
    *(uint4*)&Ah[srow * 40 + sk8] = *(const uint4*)&h_hi[(size_t)(m0 + srow) * 256 + k0 + sk8];
    *(uint4*)&Al[srow * 40 + sk8] = *(const uint4*)&h_lo[(size_t)(m0 + srow) * 256 + k0 + sk8];
    #pragma unroll
    for (int i = 0; i < 4; ++i) {
      int task = tid + 256 * i;
      int brow = task >> 2, c8 = (task & 3) * 8;
      *(uint4*)&Bh[brow * 40 + c8] = *(const uint4*)&wg_hi[(size_t)brow * 256 + k0 + c8];
      *(uint4*)&Bl[brow * 40 + c8] = *(const uint4*)&wg_lo[(size_t)brow * 256 + k0 + c8];
    }
    __syncthreads();
    short8 ah[4], al[4];
    #pragma unroll
    for (int mf = 0; mf < 4; ++mf) {
      ah[mf] = *(const short8*)&Ah[(16 * mf + lm) * 40 + 8 * lg];
      al[mf] = *(const short8*)&Al[(16 * mf + lm) * 40 + 8 * lg];
    }
    #pragma unroll
    for (int nf = 0; nf < 4; ++nf) {
      short8 bh = *(const short8*)&Bh[(64 * wv + 16 * nf + lm) * 40 + 8 * lg];
      short8 bl = *(const short8*)&Bl[(64 * wv + 16 * nf + lm) * 40 + 8 * lg];
      #pragma unroll
      for (int mf = 0; mf < 4; ++mf) {
        acc[mf][nf] = __builtin_amdgcn_mfma_f32_16x16x32_bf16(ah[mf], bh, acc[mf][nf], 0, 0, 0);
        acc[mf][nf] = __builtin_amdgcn_mfma_f32_16x16x32_bf16(ah[mf], bl, acc[mf][nf], 0, 0, 0);
        acc[mf][nf] = __builtin_amdgcn_mfma_f32_16x16x32_bf16(al[mf], bh, acc[mf][nf], 0, 0, 0);
      }
    }
  }
  #pragma unroll
  for (int nf = 0; nf < 4; ++nf) {
    int col = 64 * wv + 16 * nf + lm;
    float b = bias[col];
    #pragma unroll
    for (int mf = 0; mf < 4; ++mf) {
      #pragma unroll
      for (int r = 0; r < 4; ++r) {
        int row = m0 + 16 * mf + 4 * lg + r;
        g[(size_t)row * 256 + col] = acc[mf][nf][r] + b;
      }
    }
  }
}

// ---------------- per-node contiguous gather (no atomics) ----------------
__global__ __launch_bounds__(256) void k_gather(
    const ushort* __restrict__ h_hi, const ushort* __restrict__ h_lo,
    const float* __restrict__ g,      // [ce,256] chunk-local: gr|gv (bias incl)
    const int* __restrict__ rowstart,
    const int* __restrict__ src_s,
    const float* __restrict__ rn_s,
    const float* __restrict__ v_n,
    const float* __restrict__ icnt,
    int e0, int ce,
    float* __restrict__ hsum, float* __restrict__ v_next)
{
  int t = blockIdx.x;
  int lo = rowstart[t], hi = rowstart[t + 1];
  if (lo < e0) lo = e0;
  int e1 = e0 + ce;
  if (hi > e1) hi = e1;
  if (lo >= hi) return;
  int tid = threadIdx.x;
  int k = tid & 127, half = tid >> 7;
  float hacc = 0.0f, a0 = 0.0f, a1 = 0.0f, a2 = 0.0f;
  for (int p = lo; p < hi; ++p) {
    int lp = p - e0;
    hacc += bf2f(h_hi[(size_t)lp * SD + tid]) + bf2f(h_lo[(size_t)lp * SD + tid]);
    float gr = g[(size_t)lp * SD + k];
    float gv = g[(size_t)lp * SD + 128 + k];
    int sn = src_s[p];
    const float* vs = &v_n[(size_t)sn * 384];
    if (half == 0) {
      float r0 = rn_s[(size_t)p * 4 + 0];
      float r2 = rn_s[(size_t)p * 4 + 2];
      a0 += gr * r0 + gv * vs[k];
      a2 += gr * r2 + gv * vs[256 + k];
    } else {
      float r1 = rn_s[(size_t)p * 4 + 1];
      a1 += gr * r1 + gv * vs[128 + k];
    }
  }
  hsum[(size_t)t * SD + tid] += hacc;
  float ic = icnt[t];
  if (half == 0) {
    v_next[(size_t)t * 384 + k]       += ic * a0;
    v_next[(size_t)t * 384 + 256 + k] += ic * a2;
  } else {
    v_next[(size_t)t * 384 + 128 + k] += ic * a1;
  }
}

// ---------------- nv = sqrt(sum_c vv^2 + eps); xcat = [s | nv] ----------------
__global__ __launch_bounds__(256) void k_nv_xcat(
    const float* __restrict__ vv, const float* __restrict__ s_next,
    float* __restrict__ xcat)
{
  int n = blockIdx.x, t = threadIdx.x;
  xcat[(size_t)n * 384 + t] = s_next[(size_t)n * SD + t];
  if (t < 128) {
    float a = vv[(size_t)(n * 3 + 0) * VD + t];
    float b = vv[(size_t)(n * 3 + 1) * VD + t];
    float c = vv[(size_t)(n * 3 + 2) * VD + t];
    xcat[(size_t)n * 384 + 256 + t] = sqrtf(a * a + b * b + c * c + 1e-6f);
  }
}

// ---------------- s_cur = s_next + u[:, :256]; v_cur = v_next + vv * u[:, None, 256:] ----------------
__global__ __launch_bounds__(256) void k_update(
    const float* __restrict__ s_next, const float* __restrict__ v_next,
    const float* __restrict__ vv, const float* __restrict__ u,
    float* __restrict__ s_cur, float* __restrict__ v_cur)
{
  int i = blockIdx.x * 256 + threadIdx.x;
  const int NVT = NN * 384;
  if (i < NVT) {
    int n = i / 384;
    int k = (i - n * 384) & 127;
    v_cur[i] = v_next[i] + vv[i] * u[(size_t)n * 384 + 256 + k];
  } else {
    int j = i - NVT;
    if (j < NN * SD) {
      int n = j >> 8, c = j & 255;
      s_cur[j] = s_next[j] + u[(size_t)n * 384 + c];
    }
  }
}

// =====================================================================
extern "C" void kernel_launch(void* const* d_in, const int* in_sizes, int n_in,
                              void* d_out, int out_size, void* d_ws, size_t ws_size,
                              hipStream_t stream)
{
  const float* s_in   = (const float*)d_in[0];
  const float* v_in   = (const float*)d_in[1];
  const float* p_in   = (const float*)d_in[2];
  const int*   eidx   = (const int*)d_in[3];
  const float* edge_d = (const float*)d_in[4];
  const float* edge_a = (const float*)d_in[5];
  const float* rnorm  = (const float*)d_in[6];
  const float* edge_e = (const float*)d_in[7];
  const float* edge_o = (const float*)d_in[8];
  const float* edge_g = (const float*)d_in[9];
  const float* gamma  = (const float*)d_in[10];
  const float* beta   = (const float*)d_in[11];
  const float* We1    = (const float*)d_in[12];
  const float* be1    = (const float*)d_in[13];
  const float* We2    = (const float*)d_in[14];
  const float* be2    = (const float*)d_in[15];
  const float* Wvu    = (const float*)d_in[16];
  const float* Wu1    = (const float*)d_in[17];
  const float* bu1    = (const float*)d_in[18];
  const float* Wu2    = (const float*)d_in[19];
  const float* bu2    = (const float*)d_in[20];
  const int* srcA = eidx;
  const int* tgtA = eidx + NE;

  float* w = (float*)d_ws;
  float* s_cur  = w; w += NN * SD;
  float* v_cur  = w; w += NN * 384;
  float* s_ln   = w; w += NN * SD;      // reused later as tbuf
  float* v_nrm  = w; w += NN * 384;     // reused later as ubuf
  float* s_next = w; w += NN * SD;
  float* v_next = w; w += NN * 384;
  float* pre12  = w; w += NN * 512;     // reused later as xcat (N*384)
  float* rbfE   = w; w += (size_t)NE * 20;
  float* cnt    = w; w += NN;
  float* icnt   = w; w += NN;
  float* vv     = w; w += NN * 384;
  float* hsum   = w; w += NN * SD;
  ushort* wg_hi = (ushort*)w; w += 32768;   // 256*256 bf16
  ushort* wg_lo = (ushort*)w; w += 32768;
  ushort* wt_hi = (ushort*)w; w += 65536;   // up to 512*256 bf16 (node weights)
  ushort* wt_lo = (ushort*)w; w += 65536;
  int*   rowstart = (int*)w; w += NN + 4;   // padded to keep 16B alignment
  int*   fill     = (int*)w; w += NN;
  int*   eperm    = (int*)w; w += NE;
  int*   src_s    = (int*)w; w += NE;
  int*   tgt_s    = (int*)w; w += NE;
  float* rn_s   = w; w += (size_t)NE * 4;
  float* tbuf = s_ln;
  float* ubuf = v_nrm;
  float* xcat = pre12;

  // chunking: per chunk need chunkE*256 ushort (h_hi) + same (h_lo) + chunkE*256
  // float (g) = chunkE*512 floats total in the remainder
  size_t fixedF = (size_t)(w - (float*)d_ws);
  size_t totalF = ws_size / sizeof(float);
  size_t availF = (totalF > fixedF) ? (totalF - fixedF) : 0;
  long long mc = (long long)(availF / 512) & ~127LL;   // multiple of 128 edges
  if (mc > NE) mc = NE;
  if (mc < 128) mc = 128;
  const int chunkE = (int)mc;
  ushort* h_hi = (ushort*)w;
  ushort* h_lo = h_hi + (size_t)chunkE * SD;
  float*  gbuf = (float*)(h_lo + (size_t)chunkE * SD);

  hipMemsetAsync(cnt, 0, NN * sizeof(float), stream);
  hipMemsetAsync(fill, 0, NN * sizeof(int), stream);
  k_setup<<<(NE + 255) / 256, 256, 0, stream>>>(edge_d, tgtA, rbfE, cnt);
  k_scan<<<1, 256, 0, stream>>>(cnt, rowstart);
  k_invcnt<<<(NN + 255) / 256, 256, 0, stream>>>(cnt, icnt);
  k_place<<<(NE + 255) / 256, 256, 0, stream>>>(srcA, tgtA, rnorm, rowstart, fill,
                                                eperm, src_s, tgt_s, rn_s);

  const int MT = 157;   // ceil(10000/64)
  const float* sp = s_in;
  const float* vp = v_in;
  for (int i = 0; i < 5; ++i) {
    k_ln_vnorm<<<NN, 256, 0, stream>>>(sp, vp, gamma + i * SD, beta + i * SD,
                                       s_ln, s_next, v_nrm, v_next);
    const float* W1 = We1 + (size_t)i * DIN_ * SD;
    const float* W2 = We2 + (size_t)i * SD * 512;
    k_w2bf<<<256, 256, 0, stream>>>(W2, wg_hi, wg_lo);
    // pre12 = s_ln @ [W1a | W1b]  (combined N=512, K=256) via MFMA
    k_wsplit<<<256, 256, 0, stream>>>(W1, SD, 256, 0, wt_hi, wt_lo);
    k_wsplit<<<256, 256, 0, stream>>>(W1 + 256 * SD, SD, 256, 256, wt_hi, wt_lo);
    k_gemm_mf<0, 0><<<dim3(8, MT), 256, 0, stream>>>(
        s_ln, SD, wt_hi, wt_lo, nullptr, nullptr, nullptr, pre12, 512, NN, 256);
    hipMemsetAsync(hsum, 0, (size_t)NN * SD * sizeof(float), stream);
    for (int e0 = 0; e0 < NE; e0 += chunkE) {
      int ce = NE - e0; if (ce > chunkE) ce = chunkE;
      k_h<<<ce / 32, 256, 0, stream>>>(rbfE, edge_a, edge_e, edge_o, edge_g,
                                       eperm, src_s, tgt_s, pre12, W1 + 512 * SD,
                                       be1 + i * SD, e0, h_hi, h_lo);
      k_gmfma<<<ce / 64, 256, 0, stream>>>(h_hi, h_lo, wg_hi, wg_lo,
                                           be2 + i * 512 + 256, gbuf);
      k_gather<<<NN, 256, 0, stream>>>(h_hi, h_lo, gbuf, rowstart, src_s, rn_s,
                                       v_nrm, icnt, e0, ce, hsum, v_next);
    }
    // s_next += (hsum @ We2[:,0:256] + cnt*be2[0:256]) * icnt  via MFMA
    k_wsplit<<<256, 256, 0, stream>>>(W2, 512, 256, 0, wt_hi, wt_lo);
    k_gemm_mf<0, 1><<<dim3(4, MT), 256, 0, stream>>>(
        hsum, SD, wt_hi, wt_lo, be2 + i * 512, cnt, icnt, s_next, SD, NN, 256);
    if (i < 4) {
      // vv = v_next(30000x128) @ Wvu
      k_wsplit<<<128, 256, 0, stream>>>(Wvu + i * VD * VD, VD, VD, 0, wt_hi, wt_lo);
      k_gemm_mf<0, 0><<<dim3(2, 469), 256, 0, stream>>>(
          v_next, VD, wt_hi, wt_lo, nullptr, nullptr, nullptr, vv, VD, 3 * NN, VD);
      k_nv_xcat<<<NN, 256, 0, stream>>>(vv, s_next, xcat);
      // tbuf = silu(xcat @ Wu1 + bu1)   (K=384)
      k_wsplit<<<256, 256, 0, stream>>>(Wu1 + (size_t)i * 384 * SD, SD, 384, 0, wt_hi, wt_lo);
      k_gemm_mf<1, 0><<<dim3(4, MT), 256, 0, stream>>>(
          xcat, 384, wt_hi, wt_lo, bu1 + i * SD, nullptr, nullptr, tbuf, SD, NN, 384);
      // ubuf = tbuf @ Wu2 + bu2   (N=384)
      k_wsplit<<<384, 256, 0, stream>>>(Wu2 + (size_t)i * SD * 384, 384, 256, 0, wt_hi, wt_lo);
      k_gemm_mf<0, 0><<<dim3(6, MT), 256, 0, stream>>>(
          tbuf, SD, wt_hi, wt_lo, bu2 + i * 384, nullptr, nullptr, ubuf, 384, NN, 256);
      k_update<<<(NN * 640 + 255) / 256, 256, 0, stream>>>(s_next, v_next, vv, ubuf,
                                                           s_cur, v_cur);
      sp = s_cur; vp = v_cur;
    }
  }
  float* out = (float*)d_out;
  k_ln_vnorm<<<NN, 256, 0, stream>>>(s_next, v_next, gamma + 5 * SD, beta + 5 * SD,
                                     out, nullptr, out + NN * SD, nullptr);
  float* outp = out + (size_t)NN * SD + (size_t)NN * 384;
  hipMemcpyAsync(outp, p_in, NN * 3 * sizeof(float), hipMemcpyDeviceToDevice, stream);
  hipMemcpyAsync(outp + NN * 3, edge_e, (size_t)NE * 32 * sizeof(float),
                 hipMemcpyDeviceToDevice, stream);
}